// Round 11
// baseline (1068.107 us; speedup 1.0000x reference)
//
#include <hip/hip_runtime.h>
#include <hip/hip_bf16.h>
#include <stdint.h>

typedef unsigned short u16;
typedef uint32_t u32;
typedef unsigned long long u64;

__device__ __forceinline__ float bf2f(u16 u) {
    return __uint_as_float(((uint32_t)u) << 16);
}
__device__ __forceinline__ u16 f2bf(float f) {
    uint32_t u = __float_as_uint(f);
    uint32_t r = u + 0x7fffu + ((u >> 16) & 1u);
    return (u16)(r >> 16);
}

__device__ __forceinline__ float ldf(const float* p) { return *p; }
__device__ __forceinline__ float ldf(const u16* p) { return bf2f(*p); }

#define DEG_SCALE 4294967296.0f           // 2^32
#define DEG_INV 2.3283064365386963e-10f   // 2^-32

// bucket partition geometry (src index must fit 17 bits: n <= 131072)
#define BSHIFT 9
#define BSIZE 512
#define CAP 19456      // per-bucket capacity; mean E/NB ~= 16326, 24 sigma headroom

// ---------------- zero out[] + init bucket write pointers ----------------
__global__ void k_zero(float* out, int n, u32* bwptr, int NB) {
    int i = blockIdx.x * 256 + threadIdx.x;
    if (i < n) out[i] = 0.0f;
    if (blockIdx.x == 0 && threadIdx.x < NB) bwptr[threadIdx.x] = (u32)threadIdx.x * CAP;
}

// ---------------- 32-row GEMM tile on caller-provided 32KB LDS ----------------
// Output written to XCD-sharded layout: ch c -> shard c>>4, tbuf[s*n16 + row*16 + (c&15)]
template <typename TIn>
__device__ __forceinline__ void gemm_block(float* smem, const TIn* __restrict__ A,
                                           const float* __restrict__ W,
                                           u16* __restrict__ outp, int n, int n16, int bid) {
    float (*As)[128] = (float(*)[128])smem;             // 16KB
    float (*Ws)[128] = (float(*)[128])(smem + 32 * 128); // 16KB
    int t = threadIdx.x;
    int row0 = bid * 32;

    if constexpr (sizeof(TIn) == 2) {
        for (int i = t; i < 32 * 64; i += 256) {
            int r = i >> 6, c2 = i & 63;
            int gr = row0 + r;
            uint32_t u = (gr < n) ? *reinterpret_cast<const uint32_t*>(&A[(size_t)gr * 128 + 2 * c2]) : 0u;
            As[r][2 * c2] = bf2f((u16)(u & 0xffff));
            As[r][2 * c2 + 1] = bf2f((u16)(u >> 16));
        }
    } else {
        for (int i = t; i < 32 * 128; i += 256) {
            int r = i >> 7, c = i & 127;
            int gr = row0 + r;
            As[r][c] = (gr < n) ? ldf(&A[(size_t)gr * 128 + c]) : 0.0f;
        }
    }

    float acc[4][4];
#pragma unroll
    for (int i = 0; i < 4; i++)
#pragma unroll
        for (int j = 0; j < 4; j++) acc[i][j] = 0.0f;

    int c0 = (t & 31) * 4;
    int r0 = (t >> 5) * 4;

    for (int kt = 0; kt < 128; kt += 32) {
        __syncthreads();
        for (int i = t; i < 32 * 128; i += 256) {
            int kk = i >> 7, c = i & 127;
            Ws[kk][c] = W[(size_t)(kt + kk) * 128 + c];
        }
        __syncthreads();
#pragma unroll
        for (int kk = 0; kk < 32; kk += 4) {
            float w0[4], w1[4], w2[4], w3[4];
            *(float4*)w0 = *(const float4*)&Ws[kk + 0][c0];
            *(float4*)w1 = *(const float4*)&Ws[kk + 1][c0];
            *(float4*)w2 = *(const float4*)&Ws[kk + 2][c0];
            *(float4*)w3 = *(const float4*)&Ws[kk + 3][c0];
#pragma unroll
            for (int i = 0; i < 4; i++) {
                float a[4];
                *(float4*)a = *(const float4*)&As[r0 + i][kt + kk];
#pragma unroll
                for (int j = 0; j < 4; j++) {
                    acc[i][j] = fmaf(a[0], w0[j], acc[i][j]);
                    acc[i][j] = fmaf(a[1], w1[j], acc[i][j]);
                    acc[i][j] = fmaf(a[2], w2[j], acc[i][j]);
                    acc[i][j] = fmaf(a[3], w3[j], acc[i][j]);
                }
            }
        }
    }

    u16* obase = outp + (size_t)(c0 >> 4) * n16 + (c0 & 15);
#pragma unroll
    for (int i = 0; i < 4; i++) {
        int gr = row0 + r0 + i;
        if (gr < n) {
            ushort4 o;
            o.x = f2bf(acc[i][0]);
            o.y = f2bf(acc[i][1]);
            o.z = f2bf(acc[i][2]);
            o.w = f2bf(acc[i][3]);
            *reinterpret_cast<ushort4*>(obase + (size_t)gr * 16) = o;
        }
    }
}

// ---------------- fused: 1:1 role-split [gemm | edge partition] ----------------
// even bid -> gemm tile bid/2; odd bid -> partition chunk bid/2
__global__ __launch_bounds__(256) void k_part_gemm(const float* __restrict__ x, const float* __restrict__ W1,
                                                   u16* __restrict__ tbuf, int n, int n16, int Gg,
                                                   const int* __restrict__ src, const int* __restrict__ dst,
                                                   const float* __restrict__ ew,
                                                   u32* bwptr, u64* __restrict__ ebuf,
                                                   int E, int EPB, int NB) {
    __shared__ float smem[2 * 32 * 128];   // 32KB, unioned across roles
    int bid = blockIdx.x;
    int t = threadIdx.x;
    if ((bid & 1) == 0) {
        int gb = bid >> 1;
        if (gb < Gg) gemm_block<float>(smem, x, W1, tbuf, n, n16, gb);
        return;
    }
    int pb = bid >> 1;
    u32* hist = (u32*)smem;
    u32* base = (u32*)smem + 256;
    if (t < NB) hist[t] = 0;
    __syncthreads();
    int e0 = pb * EPB;
    int e1 = min(e0 + EPB, E);
    if (e0 >= E) return;
    for (int e = e0 + t; e < e1; e += 256) {
        atomicAdd(&hist[dst[e] >> BSHIFT], 1u);
    }
    __syncthreads();
    if (t < NB) {
        base[t] = atomicAdd(&bwptr[t], hist[t]);
        hist[t] = 0;
    }
    __syncthreads();
    for (int e = e0 + t; e < e1; e += 256) {
        int d = dst[e];
        int b = d >> BSHIFT;
        u32 pos = base[b] + atomicAdd(&hist[b], 1u);
        u32 w0 = (u32)src[e] | ((u32)(d & (BSIZE - 1)) << 17);
        ebuf[pos] = (u64)w0 | ((u64)__float_as_uint(ew[e]) << 32);
    }
}

// ---------------- per-bucket: degcnt in LDS + dinv + bucket-local rowptr ----------------
__global__ __launch_bounds__(512) void k_bucket(const u64* __restrict__ ebuf, const u32* __restrict__ bwptr,
                                                u64* __restrict__ packed, float* __restrict__ dinv,
                                                int* __restrict__ rowptr, int n) {
    __shared__ u64 acc[BSIZE];
    __shared__ int sc[BSIZE];
    int b = blockIdx.x;
    int t = threadIdx.x;
    acc[t] = 0;
    __syncthreads();
    int cnt = (int)(bwptr[b] - (u32)b * CAP);
    const u64* eb = ebuf + (size_t)b * CAP;
    for (int e = t; e < cnt; e += 512) {
        u64 w = eb[e];
        int dlow = ((u32)w >> 17) & (BSIZE - 1);
        float wv = __uint_as_float((u32)(w >> 32));
        atomicAdd(&acc[dlow], (1ull << 48) | (u64)(wv * DEG_SCALE));
    }
    __syncthreads();
    u64 pk = acc[t] + (1ull << 32);     // + self-loop weight 1.0
    int c = (int)(pk >> 48);
    sc[t] = c;
    __syncthreads();
    for (int off = 1; off < 512; off <<= 1) {
        int x = (t >= off) ? sc[t - off] : 0;
        __syncthreads();
        sc[t] += x;
        __syncthreads();
    }
    int node = (b << BSHIFT) + t;
    if (node < n) {
        packed[node] = pk;
        dinv[node] = rsqrtf((float)(pk & 0xFFFFFFFFFFFFull) * DEG_INV);
        rowptr[node] = b * CAP + (sc[t] - c);   // bucket-local exclusive scan
    }
}

// ---------------- per-bucket scatter into CSR (L2-local rec writes) ----------------
__global__ __launch_bounds__(512) void k_bscatter(const u64* __restrict__ ebuf, const u32* __restrict__ bwptr,
                                                  const int* __restrict__ rowptr, const float* __restrict__ dinv,
                                                  int2* __restrict__ rec, int n) {
    __shared__ u32 fill[BSIZE];
    __shared__ int rp[BSIZE];
    __shared__ float din[BSIZE];
    int b = blockIdx.x;
    int t = threadIdx.x;
    int node0 = b << BSHIFT;
    for (int i = t; i < BSIZE; i += 512) {
        int node = node0 + i;
        fill[i] = 0;
        rp[i] = (node < n) ? rowptr[node] : 0;
        din[i] = (node < n) ? dinv[node] : 0.f;
    }
    __syncthreads();
    int cnt = (int)(bwptr[b] - (u32)b * CAP);
    const u64* eb = ebuf + (size_t)b * CAP;
    for (int e = t; e < cnt; e += 512) {
        u64 w = eb[e];
        u32 lo = (u32)w;
        int s = lo & 0x1FFFF;
        int dlow = (lo >> 17) & (BSIZE - 1);
        float ewv = __uint_as_float((u32)(w >> 32));
        float nrm = dinv[s] * ewv * din[dlow];
        int pos = rp[dlow] + (int)atomicAdd(&fill[dlow], 1u);
        rec[pos] = make_int2(s, __float_as_int(nrm));
    }
}

// ---------------- standalone gemm (layer 2) ----------------
template <typename TIn>
__global__ __launch_bounds__(256) void k_gemm(const TIn* __restrict__ A, const float* __restrict__ W,
                                              u16* __restrict__ outp, int n, int n16) {
    __shared__ float smem[2 * 32 * 128];
    gemm_block<TIn>(smem, A, W, outp, n, n16, blockIdx.x);
}

// ---------------- XCD-sharded aggregation ----------------
// shard s = blockIdx & 7 (round-robin block->XCD => shard L2-resident, 3.2MB < 4MB L2/XCD)
// block: 4 waves = 4 nodes; wave: 32 edge slots x 2 lanes; lane handles 8 ch (16B gather)
// MODE 0: relu(agg)+bias -> hout row-major.  MODE 1: FC partial -> atomicAdd(out[node]).
template <int MODE>
__global__ __launch_bounds__(256) void k_agg(const u16* __restrict__ t, const int2* __restrict__ rec,
                                             const int* __restrict__ rowptr, const u64* __restrict__ packed,
                                             const float* __restrict__ dinv, const float* __restrict__ bias,
                                             u16* __restrict__ hout,
                                             const float* __restrict__ action, const float* __restrict__ Wfc,
                                             const float* __restrict__ bfc, float* __restrict__ out,
                                             int n, int n16) {
    int bid = blockIdx.x;
    int s = bid & 7;
    int g = bid >> 3;
    int node = g * 4 + (threadIdx.x >> 6);
    if (node >= n) return;
    int lane = threadIdx.x & 63;
    int slot = lane >> 1;
    int h = lane & 1;
    const u16* ts = t + (size_t)s * n16;
    int base = rowptr[node];
    int m = (int)(packed[node] >> 48);

    float a0 = 0.f, a1 = 0.f, a2 = 0.f, a3 = 0.f, a4 = 0.f, a5 = 0.f, a6 = 0.f, a7 = 0.f;

#define ACCUM(G, NN)                                                         \
    {                                                                        \
        float nv = (NN);                                                     \
        a0 = fmaf(nv, __uint_as_float((G).x << 16), a0);                     \
        a1 = fmaf(nv, __uint_as_float((G).x & 0xFFFF0000u), a1);             \
        a2 = fmaf(nv, __uint_as_float((G).y << 16), a2);                     \
        a3 = fmaf(nv, __uint_as_float((G).y & 0xFFFF0000u), a3);             \
        a4 = fmaf(nv, __uint_as_float((G).z << 16), a4);                     \
        a5 = fmaf(nv, __uint_as_float((G).z & 0xFFFF0000u), a5);             \
        a6 = fmaf(nv, __uint_as_float((G).w << 16), a6);                     \
        a7 = fmaf(nv, __uint_as_float((G).w & 0xFFFF0000u), a7);             \
    }

    for (int e = 0; e < m; e += 32) {
        int ei = e + slot;
        int2 r = (ei < m) ? rec[base + ei] : make_int2(0, 0);
        uint4 gv = *reinterpret_cast<const uint4*>(ts + ((u32)r.x * 16 + h * 8));
        ACCUM(gv, __int_as_float(r.y));
    }

    // reduce across the 32 edge slots (preserve h = bit 0)
#define RED(A)                                   \
    A += __shfl_xor(A, 2, 64);                   \
    A += __shfl_xor(A, 4, 64);                   \
    A += __shfl_xor(A, 8, 64);                   \
    A += __shfl_xor(A, 16, 64);                  \
    A += __shfl_xor(A, 32, 64);
    RED(a0) RED(a1) RED(a2) RED(a3) RED(a4) RED(a5) RED(a6) RED(a7)
#undef RED

    if (slot == 0) {   // lanes 0 (h=0: ch s*16+0..7) and 1 (h=1: ch s*16+8..15)
        float di = dinv[node];
        float sdi = di * di;
        uint4 sv = *reinterpret_cast<const uint4*>(ts + ((u32)node * 16 + h * 8));
        ACCUM(sv, sdi);
        int cb = s * 16 + h * 8;
        float4 b0 = *reinterpret_cast<const float4*>(&bias[cb]);
        float4 b1 = *reinterpret_cast<const float4*>(&bias[cb + 4]);
        a0 = fmaxf(a0 + b0.x, 0.f); a1 = fmaxf(a1 + b0.y, 0.f);
        a2 = fmaxf(a2 + b0.z, 0.f); a3 = fmaxf(a3 + b0.w, 0.f);
        a4 = fmaxf(a4 + b1.x, 0.f); a5 = fmaxf(a5 + b1.y, 0.f);
        a6 = fmaxf(a6 + b1.z, 0.f); a7 = fmaxf(a7 + b1.w, 0.f);
        if (MODE == 0) {
            uint4 o;
            o.x = (u32)f2bf(a0) | ((u32)f2bf(a1) << 16);
            o.y = (u32)f2bf(a2) | ((u32)f2bf(a3) << 16);
            o.z = (u32)f2bf(a4) | ((u32)f2bf(a5) << 16);
            o.w = (u32)f2bf(a6) | ((u32)f2bf(a7) << 16);
            *reinterpret_cast<uint4*>(hout + (size_t)node * 128 + cb) = o;
        } else {
            float4 w0 = *reinterpret_cast<const float4*>(&Wfc[cb]);
            float4 w1 = *reinterpret_cast<const float4*>(&Wfc[cb + 4]);
            float v = a0 * w0.x + a1 * w0.y + a2 * w0.z + a3 * w0.w +
                      a4 * w1.x + a5 * w1.y + a6 * w1.z + a7 * w1.w;
            v += __shfl_xor(v, 1, 64);    // lanes 0,1 both active
            if (lane == 0) {
                float extra = (s == 0) ? action[node] * Wfc[128] + bfc[0] : 0.f;
                atomicAdd(&out[node], v + extra);
            }
        }
    }
#undef ACCUM
}

extern "C" void kernel_launch(void* const* d_in, const int* in_sizes, int n_in,
                              void* d_out, int out_size, void* d_ws, size_t ws_size,
                              hipStream_t stream) {
    const float* x = (const float*)d_in[0];
    const int* ei = (const int*)d_in[1];
    const float* ew = (const float*)d_in[2];
    const float* action = (const float*)d_in[3];
    const float* W1 = (const float*)d_in[4];
    const float* b1 = (const float*)d_in[5];
    const float* W2 = (const float*)d_in[6];
    const float* b2 = (const float*)d_in[7];
    const float* Wfc = (const float*)d_in[8];
    const float* bfc = (const float*)d_in[9];
    float* out = (float*)d_out;

    int n = in_sizes[0] / 128;
    int E = in_sizes[2];
    const int* src = ei;
    const int* dst = ei + E;
    int n16 = n * 16;

    char* p = (char*)d_ws;
    auto carve = [&](size_t bytes) -> char* {
        char* q = p;
        p += (bytes + 255) & ~(size_t)255;
        return q;
    };
    int NB = (n + BSIZE - 1) >> BSHIFT;      // 196 buckets
    u64* packed = (u64*)carve((size_t)n * 8);
    float* dinv = (float*)carve((size_t)n * 4);
    int* rowptr = (int*)carve((size_t)n * 4);
    u32* bwptr = (u32*)carve((size_t)NB * 4);
    u64* ebuf = (u64*)carve((size_t)NB * CAP * 8);
    int2* rec = (int2*)carve((size_t)NB * CAP * 8);   // bucket-local addressing
    u16* tbuf = (u16*)carve((size_t)n * 128 * 2);     // sharded [8][n][16]
    u16* hbuf = (u16*)carve((size_t)n * 128 * 2);     // row-major [n][128]

    int Gg = (n + 31) / 32;                  // 3125 gemm tiles / partition chunks
    int EPB = (E + Gg - 1) / Gg;             // 1024 edges per partition block

    k_zero<<<(n + 255) / 256, 256, 0, stream>>>(out, n, bwptr, NB);
    k_part_gemm<<<2 * Gg, 256, 0, stream>>>(x, W1, tbuf, n, n16, Gg, src, dst, ew,
                                            bwptr, ebuf, E, EPB, NB);
    k_bucket<<<NB, 512, 0, stream>>>(ebuf, bwptr, packed, dinv, rowptr, n);
    k_bscatter<<<NB, 512, 0, stream>>>(ebuf, bwptr, rowptr, dinv, rec, n);

    int aggGrid = 8 * ((n + 3) / 4);
    k_agg<0><<<aggGrid, 256, 0, stream>>>(tbuf, rec, rowptr, packed, dinv, b1, hbuf,
                                          nullptr, nullptr, nullptr, nullptr, n, n16);
    k_gemm<u16><<<Gg, 256, 0, stream>>>(hbuf, W2, tbuf, n, n16);
    k_agg<1><<<aggGrid, 256, 0, stream>>>(tbuf, rec, rowptr, packed, dinv, b2, nullptr,
                                          action, Wfc, bfc, out, n, n16);
}

// Round 13
// 547.387 us; speedup vs baseline: 1.9513x; 1.9513x over previous
//
#include <hip/hip_runtime.h>
#include <hip/hip_bf16.h>
#include <stdint.h>

typedef unsigned short u16;
typedef uint32_t u32;
typedef unsigned long long u64;

__device__ __forceinline__ float bf2f(u16 u) {
    return __uint_as_float(((uint32_t)u) << 16);
}
__device__ __forceinline__ u16 f2bf(float f) {
    uint32_t u = __float_as_uint(f);
    uint32_t r = u + 0x7fffu + ((u >> 16) & 1u);
    return (u16)(r >> 16);
}

__device__ __forceinline__ float ldf(const float* p) { return *p; }
__device__ __forceinline__ float ldf(const u16* p) { return bf2f(*p); }

#define DEG_SCALE 4294967296.0f           // 2^32
#define DEG_INV 2.3283064365386963e-10f   // 2^-32

// bucket partition geometry (src index must fit 17 bits: n <= 131072)
#define BSHIFT 9
#define BSIZE 512
#define CAP 19456      // per-bucket capacity; mean E/NB ~= 16326, 24 sigma headroom

// ---------------- init bucket write pointers ----------------
__global__ void k_init0(u32* bwptr, int NB) {
    int t = threadIdx.x;
    if (t < NB) bwptr[t] = (u32)t * CAP;
}

// ---------------- 32-row GEMM tile on caller-provided 32KB LDS (row-major output) ----------------
template <typename TIn>
__device__ __forceinline__ void gemm_block(float* smem, const TIn* __restrict__ A,
                                           const float* __restrict__ W,
                                           u16* __restrict__ outp, int n, int bid) {
    float (*As)[128] = (float(*)[128])smem;             // 16KB
    float (*Ws)[128] = (float(*)[128])(smem + 32 * 128); // 16KB
    int t = threadIdx.x;
    int row0 = bid * 32;

    if constexpr (sizeof(TIn) == 2) {
        for (int i = t; i < 32 * 64; i += 256) {
            int r = i >> 6, c2 = i & 63;
            int gr = row0 + r;
            uint32_t u = (gr < n) ? *reinterpret_cast<const uint32_t*>(&A[(size_t)gr * 128 + 2 * c2]) : 0u;
            As[r][2 * c2] = bf2f((u16)(u & 0xffff));
            As[r][2 * c2 + 1] = bf2f((u16)(u >> 16));
        }
    } else {
        for (int i = t; i < 32 * 128; i += 256) {
            int r = i >> 7, c = i & 127;
            int gr = row0 + r;
            As[r][c] = (gr < n) ? ldf(&A[(size_t)gr * 128 + c]) : 0.0f;
        }
    }

    float acc[4][4];
#pragma unroll
    for (int i = 0; i < 4; i++)
#pragma unroll
        for (int j = 0; j < 4; j++) acc[i][j] = 0.0f;

    int c0 = (t & 31) * 4;
    int r0 = (t >> 5) * 4;

    for (int kt = 0; kt < 128; kt += 32) {
        __syncthreads();
        for (int i = t; i < 32 * 128; i += 256) {
            int kk = i >> 7, c = i & 127;
            Ws[kk][c] = W[(size_t)(kt + kk) * 128 + c];
        }
        __syncthreads();
#pragma unroll
        for (int kk = 0; kk < 32; kk += 4) {
            float w0[4], w1[4], w2[4], w3[4];
            *(float4*)w0 = *(const float4*)&Ws[kk + 0][c0];
            *(float4*)w1 = *(const float4*)&Ws[kk + 1][c0];
            *(float4*)w2 = *(const float4*)&Ws[kk + 2][c0];
            *(float4*)w3 = *(const float4*)&Ws[kk + 3][c0];
#pragma unroll
            for (int i = 0; i < 4; i++) {
                float a[4];
                *(float4*)a = *(const float4*)&As[r0 + i][kt + kk];
#pragma unroll
                for (int j = 0; j < 4; j++) {
                    acc[i][j] = fmaf(a[0], w0[j], acc[i][j]);
                    acc[i][j] = fmaf(a[1], w1[j], acc[i][j]);
                    acc[i][j] = fmaf(a[2], w2[j], acc[i][j]);
                    acc[i][j] = fmaf(a[3], w3[j], acc[i][j]);
                }
            }
        }
    }

#pragma unroll
    for (int i = 0; i < 4; i++) {
        int gr = row0 + r0 + i;
        if (gr < n) {
            ushort4 o;
            o.x = f2bf(acc[i][0]);
            o.y = f2bf(acc[i][1]);
            o.z = f2bf(acc[i][2]);
            o.w = f2bf(acc[i][3]);
            *reinterpret_cast<ushort4*>(&outp[(size_t)gr * 128 + c0]) = o;
        }
    }
}

// ---------------- fused: [gemm1 | edge partition], UNIFORM work, 3:2 role mix (R8-proven) ----------------
// group of 5 blocks: r in {0,1,2} -> gemm block 3g+r; r in {3,4} -> partition block 2g+(r-3)
__global__ __launch_bounds__(256) void k_part_gemm(const float* __restrict__ x, const float* __restrict__ W1,
                                                   u16* __restrict__ tbuf, int n, int Gg,
                                                   const int* __restrict__ src, const int* __restrict__ dst,
                                                   const float* __restrict__ ew,
                                                   u32* bwptr, u64* __restrict__ ebuf,
                                                   int E, int EPB, int NB) {
    __shared__ float smem[2 * 32 * 128];   // 32KB, unioned across roles
    int bid = blockIdx.x;
    int g = bid / 5;
    int r = bid - g * 5;
    if (r < 3) {
        int gb = 3 * g + r;
        if (gb < Gg) gemm_block<float>(smem, x, W1, tbuf, n, gb);
        return;
    }
    int pb = 2 * g + (r - 3);
    u32* hist = (u32*)smem;
    u32* base = (u32*)smem + 256;
    int t = threadIdx.x;
    if (t < NB) hist[t] = 0;
    __syncthreads();
    int e0 = pb * EPB;
    int e1 = min(e0 + EPB, E);
    if (e0 >= E) return;
    for (int e = e0 + t; e < e1; e += 256) {
        atomicAdd(&hist[dst[e] >> BSHIFT], 1u);
    }
    __syncthreads();
    if (t < NB) {
        base[t] = atomicAdd(&bwptr[t], hist[t]);
        hist[t] = 0;
    }
    __syncthreads();
    for (int e = e0 + t; e < e1; e += 256) {
        int d = dst[e];
        int b = d >> BSHIFT;
        u32 pos = base[b] + atomicAdd(&hist[b], 1u);
        u32 w0 = (u32)src[e] | ((u32)(d & (BSIZE - 1)) << 17);
        ebuf[pos] = (u64)w0 | ((u64)__float_as_uint(ew[e]) << 32);
    }
}

// ---------------- per-bucket: degcnt in LDS + dinv + bucket-local rowptr ----------------
__global__ __launch_bounds__(512) void k_bucket(const u64* __restrict__ ebuf, const u32* __restrict__ bwptr,
                                                u64* __restrict__ packed, float* __restrict__ dinv,
                                                int* __restrict__ rowptr, int n) {
    __shared__ u64 acc[BSIZE];
    __shared__ int sc[BSIZE];
    int b = blockIdx.x;
    int t = threadIdx.x;
    acc[t] = 0;
    __syncthreads();
    int cnt = (int)(bwptr[b] - (u32)b * CAP);
    const u64* eb = ebuf + (size_t)b * CAP;
    for (int e = t; e < cnt; e += 512) {
        u64 w = eb[e];
        int dlow = ((u32)w >> 17) & (BSIZE - 1);
        float wv = __uint_as_float((u32)(w >> 32));
        atomicAdd(&acc[dlow], (1ull << 48) | (u64)(wv * DEG_SCALE));
    }
    __syncthreads();
    u64 pk = acc[t] + (1ull << 32);     // + self-loop weight 1.0
    int c = (int)(pk >> 48);
    sc[t] = c;
    __syncthreads();
    for (int off = 1; off < 512; off <<= 1) {
        int x = (t >= off) ? sc[t - off] : 0;
        __syncthreads();
        sc[t] += x;
        __syncthreads();
    }
    int node = (b << BSHIFT) + t;
    if (node < n) {
        packed[node] = pk;
        dinv[node] = rsqrtf((float)(pk & 0xFFFFFFFFFFFFull) * DEG_INV);
        rowptr[node] = b * CAP + (sc[t] - c);   // bucket-local exclusive scan
    }
}

// ---------------- per-bucket scatter into CSR (L2-local rec writes) ----------------
__global__ __launch_bounds__(512) void k_bscatter(const u64* __restrict__ ebuf, const u32* __restrict__ bwptr,
                                                  const int* __restrict__ rowptr, const float* __restrict__ dinv,
                                                  int2* __restrict__ rec, int n) {
    __shared__ u32 fill[BSIZE];
    __shared__ int rp[BSIZE];
    __shared__ float din[BSIZE];
    int b = blockIdx.x;
    int t = threadIdx.x;
    int node0 = b << BSHIFT;
    for (int i = t; i < BSIZE; i += 512) {
        int node = node0 + i;
        fill[i] = 0;
        rp[i] = (node < n) ? rowptr[node] : 0;
        din[i] = (node < n) ? dinv[node] : 0.f;
    }
    __syncthreads();
    int cnt = (int)(bwptr[b] - (u32)b * CAP);
    const u64* eb = ebuf + (size_t)b * CAP;
    for (int e = t; e < cnt; e += 512) {
        u64 w = eb[e];
        u32 lo = (u32)w;
        int s = lo & 0x1FFFF;
        int dlow = (lo >> 17) & (BSIZE - 1);
        float ewv = __uint_as_float((u32)(w >> 32));
        float nrm = dinv[s] * ewv * din[dlow];
        int pos = rp[dlow] + (int)atomicAdd(&fill[dlow], 1u);
        rec[pos] = make_int2(s, __float_as_int(nrm));
    }
}

// ---------------- standalone gemm (layer 2) ----------------
template <typename TIn>
__global__ __launch_bounds__(256) void k_gemm(const TIn* __restrict__ A, const float* __restrict__ W,
                                              u16* __restrict__ outp, int n) {
    __shared__ float smem[2 * 32 * 128];
    gemm_block<TIn>(smem, A, W, outp, n, blockIdx.x);
}

// ---------------- aggregation: 16-lane group per node (4 nodes/wave, 16 nodes/block) ----------------
// lane owns 8 fixed channels end-to-end: NO cross-slot reduction in MODE 0.
// MODE 0: relu(agg)+bias -> hout bf16.  MODE 1: FC dot -> 4 intra-group shfls -> out[node].
template <int MODE>
__global__ __launch_bounds__(256) void k_agg(const u16* __restrict__ t, const int2* __restrict__ rec,
                                             const int* __restrict__ rowptr, const u64* __restrict__ packed,
                                             const float* __restrict__ dinv, const float* __restrict__ bias,
                                             u16* __restrict__ hout,
                                             const float* __restrict__ action, const float* __restrict__ Wfc,
                                             const float* __restrict__ bfc, float* __restrict__ out, int n) {
    int node = blockIdx.x * 16 + (threadIdx.x >> 4);
    if (node >= n) return;
    int gl = threadIdx.x & 15;
    int c8 = gl * 8;
    int base = rowptr[node];
    int m = (int)(packed[node] >> 48);

    float a0 = 0.f, a1 = 0.f, a2 = 0.f, a3 = 0.f, a4 = 0.f, a5 = 0.f, a6 = 0.f, a7 = 0.f;

#define ACCUM(G, NN)                                                         \
    {                                                                        \
        float nv = (NN);                                                     \
        a0 = fmaf(nv, __uint_as_float((G).x << 16), a0);                     \
        a1 = fmaf(nv, __uint_as_float((G).x & 0xFFFF0000u), a1);             \
        a2 = fmaf(nv, __uint_as_float((G).y << 16), a2);                     \
        a3 = fmaf(nv, __uint_as_float((G).y & 0xFFFF0000u), a3);             \
        a4 = fmaf(nv, __uint_as_float((G).z << 16), a4);                     \
        a5 = fmaf(nv, __uint_as_float((G).z & 0xFFFF0000u), a5);             \
        a6 = fmaf(nv, __uint_as_float((G).w << 16), a6);                     \
        a7 = fmaf(nv, __uint_as_float((G).w & 0xFFFF0000u), a7);             \
    }

    int e = 0;
    for (; e + 4 <= m; e += 4) {
        int2 r0 = rec[base + e + 0];
        int2 r1 = rec[base + e + 1];
        int2 r2 = rec[base + e + 2];
        int2 r3 = rec[base + e + 3];
        uint4 g0 = *reinterpret_cast<const uint4*>(t + (((u32)r0.x << 7) + c8));
        uint4 g1 = *reinterpret_cast<const uint4*>(t + (((u32)r1.x << 7) + c8));
        uint4 g2 = *reinterpret_cast<const uint4*>(t + (((u32)r2.x << 7) + c8));
        uint4 g3 = *reinterpret_cast<const uint4*>(t + (((u32)r3.x << 7) + c8));
        ACCUM(g0, __int_as_float(r0.y));
        ACCUM(g1, __int_as_float(r1.y));
        ACCUM(g2, __int_as_float(r2.y));
        ACCUM(g3, __int_as_float(r3.y));
    }
    for (; e < m; e++) {
        int2 r = rec[base + e];
        uint4 g = *reinterpret_cast<const uint4*>(t + (((u32)r.x << 7) + c8));
        ACCUM(g, __int_as_float(r.y));
    }

    // self loop
    float di = dinv[node];
    float sdi = di * di;
    uint4 sv = *reinterpret_cast<const uint4*>(t + (((u32)node << 7) + c8));
    ACCUM(sv, sdi);
#undef ACCUM

    float4 b0 = *reinterpret_cast<const float4*>(&bias[c8]);
    float4 b1 = *reinterpret_cast<const float4*>(&bias[c8 + 4]);
    a0 = fmaxf(a0 + b0.x, 0.f); a1 = fmaxf(a1 + b0.y, 0.f);
    a2 = fmaxf(a2 + b0.z, 0.f); a3 = fmaxf(a3 + b0.w, 0.f);
    a4 = fmaxf(a4 + b1.x, 0.f); a5 = fmaxf(a5 + b1.y, 0.f);
    a6 = fmaxf(a6 + b1.z, 0.f); a7 = fmaxf(a7 + b1.w, 0.f);

    if (MODE == 0) {
        uint4 o;
        o.x = (u32)f2bf(a0) | ((u32)f2bf(a1) << 16);
        o.y = (u32)f2bf(a2) | ((u32)f2bf(a3) << 16);
        o.z = (u32)f2bf(a4) | ((u32)f2bf(a5) << 16);
        o.w = (u32)f2bf(a6) | ((u32)f2bf(a7) << 16);
        *reinterpret_cast<uint4*>(hout + (((u32)node << 7) + c8)) = o;
    } else {
        float4 w0 = *reinterpret_cast<const float4*>(&Wfc[c8]);
        float4 w1 = *reinterpret_cast<const float4*>(&Wfc[c8 + 4]);
        float v = a0 * w0.x + a1 * w0.y + a2 * w0.z + a3 * w0.w +
                  a4 * w1.x + a5 * w1.y + a6 * w1.z + a7 * w1.w;
        v += __shfl_xor(v, 1, 64);
        v += __shfl_xor(v, 2, 64);
        v += __shfl_xor(v, 4, 64);
        v += __shfl_xor(v, 8, 64);
        if (gl == 0) out[node] = v + action[node] * Wfc[128] + bfc[0];
    }
}

extern "C" void kernel_launch(void* const* d_in, const int* in_sizes, int n_in,
                              void* d_out, int out_size, void* d_ws, size_t ws_size,
                              hipStream_t stream) {
    const float* x = (const float*)d_in[0];
    const int* ei = (const int*)d_in[1];
    const float* ew = (const float*)d_in[2];
    const float* action = (const float*)d_in[3];
    const float* W1 = (const float*)d_in[4];
    const float* b1 = (const float*)d_in[5];
    const float* W2 = (const float*)d_in[6];
    const float* b2 = (const float*)d_in[7];
    const float* Wfc = (const float*)d_in[8];
    const float* bfc = (const float*)d_in[9];
    float* out = (float*)d_out;

    int n = in_sizes[0] / 128;
    int E = in_sizes[2];
    const int* src = ei;
    const int* dst = ei + E;

    char* p = (char*)d_ws;
    auto carve = [&](size_t bytes) -> char* {
        char* q = p;
        p += (bytes + 255) & ~(size_t)255;
        return q;
    };
    int NB = (n + BSIZE - 1) >> BSHIFT;      // 196 buckets
    u64* packed = (u64*)carve((size_t)n * 8);
    float* dinv = (float*)carve((size_t)n * 4);
    int* rowptr = (int*)carve((size_t)n * 4);
    u32* bwptr = (u32*)carve((size_t)NB * 4);
    u64* ebuf = (u64*)carve((size_t)NB * CAP * 8);
    int2* rec = (int2*)carve((size_t)NB * CAP * 8);   // bucket-local addressing
    u16* tbuf = (u16*)carve((size_t)n * 128 * 2);
    u16* hbuf = (u16*)carve((size_t)n * 128 * 2);

    int Gg = (n + 31) / 32;                  // 3125 gemm tiles
    int G = (Gg + 2) / 3;                    // 1042 groups of 5 blocks
    int Gp = 2 * G;                          // 2084 partition blocks
    int EPB = (E + Gp - 1) / Gp;             // ~1536 edges per partition block

    k_init0<<<1, 256, 0, stream>>>(bwptr, NB);
    k_part_gemm<<<G * 5, 256, 0, stream>>>(x, W1, tbuf, n, Gg, src, dst, ew,
                                           bwptr, ebuf, E, EPB, NB);
    k_bucket<<<NB, 512, 0, stream>>>(ebuf, bwptr, packed, dinv, rowptr, n);
    k_bscatter<<<NB, 512, 0, stream>>>(ebuf, bwptr, rowptr, dinv, rec, n);

    k_agg<0><<<(n + 15) / 16, 256, 0, stream>>>(tbuf, rec, rowptr, packed, dinv, b1, hbuf,
                                                nullptr, nullptr, nullptr, nullptr, n);
    k_gemm<u16><<<Gg, 256, 0, stream>>>(hbuf, W2, tbuf, n);
    k_agg<1><<<(n + 15) / 16, 256, 0, stream>>>(tbuf, rec, rowptr, packed, dinv, b2, nullptr,
                                                action, Wfc, bfc, out, n);
}